// Round 12
// baseline (581.295 us; speedup 1.0000x reference)
//
#include <hip/hip_runtime.h>

// GCN: 2x GCNConv(+self-loop sym-norm) + ReLU, global mean pool, linear head.
// N=100000, E=1600000, G=100, D_IN=3, H=128, OUT=10.
//
// R11->R12: extend XCD-affinity to all edge-indexed RMWs and delete a pass:
// (1) fillagg = fill + layer-1 aggregation: matching edges also atomicAdd
//     xf4[src].xyz into u4[dst] — dst is region-filtered so these fp32
//     atomics stay in ONE XCD's L2 (R6's fillagg failed because they were
//     cross-XCD). aggu kernel + its esrc re-read eliminated.
// (2) deg counting moved into the same slice-x-region filtered pattern
//     (prep kernel, fused with dtype conversion) — last ping-pong removed.
// (3) tiny scaleu kernel finalizes u = di*(sum + x_i).
// agg2pool / scans / final unchanged from R11.
//
// All kernels static + gcn364_ prefix (cross-.so symbol collisions caused the
// round-1 silent failure). Runtime dtype probe handles bf16/fp32 harness mode.

#define DIN 3
#define H 128
#define OUTF 10
#define NWEIGHT (384 + 128 + 16384 + 128 + 1280 + 10)  // W1,b1,W2,b2,Wl,bl
#define FILL_CH 2048

typedef float gcn364_f2 __attribute__((ext_vector_type(2)));

__device__ __forceinline__ float gcn364_bf2f(unsigned short u) {
    return __uint_as_float(((unsigned int)u) << 16);
}
__device__ __forceinline__ unsigned short gcn364_f2bf(float f) {
    unsigned int u = __float_as_uint(f);
    u += 0x7FFFu + ((u >> 16) & 1u);   // round-to-nearest-even
    return (unsigned short)(u >> 16);
}

// per-wave dtype probe over x's first 256 ushorts: 1 -> fp32, 0 -> bf16.
__device__ __forceinline__ int gcn364_probe(const unsigned short* __restrict__ xs16) {
    int lane = threadIdx.x & 63;
    int outl = 0;
    #pragma unroll
    for (int k = 0; k < 4; k++) {
        unsigned short u = xs16[lane * 4 + k];
        int e = (u >> 7) & 0xFF;
        outl += (e < 100 || e > 140) ? 1 : 0;
    }
    #pragma unroll
    for (int d = 1; d < 64; d <<= 1) outl += __shfl_xor(outl, d);
    return (outl > 32) ? 1 : 0;
}

// prep: XCD-affine filtered deg count (grid = slices x 8 regions) + dtype
// conversion (first convBlocks blocks also convert a 256-item chunk of
// x -> xf4 and weights -> wf) + flag publish.
static __global__ void gcn364_prep(const void* __restrict__ x,
                                   const void* __restrict__ W1, const void* __restrict__ b1,
                                   const void* __restrict__ W2, const void* __restrict__ b2,
                                   const void* __restrict__ Wl, const void* __restrict__ bl,
                                   int* __restrict__ flag,
                                   float4* __restrict__ xf4, float* __restrict__ wf,
                                   const int* __restrict__ edst, int* __restrict__ deg,
                                   int N, int E) {
    // --- filtered degree count ---
    int r = blockIdx.x & 7;
    int s = blockIdx.x >> 3;
    int regSize = (N + 7) >> 3;
    int rlo = r * regSize;
    int rhi = rlo + regSize;
    int elo = s * FILL_CH;
    int ehi = elo + FILL_CH;
    if (ehi > E) ehi = E;
    for (int e = elo + threadIdx.x; e < ehi; e += 256) {
        int d = edst[e];
        if (d >= rlo && d < rhi) atomicAdd(&deg[d], 1);
    }
    // --- conversion chunk ---
    int i = blockIdx.x * blockDim.x + threadIdx.x;
    int total = N + NWEIGHT;
    if (blockIdx.x * 256 < total) {
        int fl = gcn364_probe((const unsigned short*)x);
        if (i == 0) *flag = fl;
        if (i < N) {
            float a, b, c;
            if (fl) {
                const float* xs = (const float*)x;
                a = xs[3 * i]; b = xs[3 * i + 1]; c = xs[3 * i + 2];
            } else {
                const unsigned short* xs = (const unsigned short*)x;
                a = gcn364_bf2f(xs[3 * i]);
                b = gcn364_bf2f(xs[3 * i + 1]);
                c = gcn364_bf2f(xs[3 * i + 2]);
            }
            xf4[i] = make_float4(a, b, c, 0.f);
        } else if (i < total) {
            int j = i - N;
            const void* srcp;
            if      (j < 384)                       { srcp = W1; }
            else if ((j -= 384)   < 128)            { srcp = b1; }
            else if ((j -= 128)   < 16384)          { srcp = W2; }
            else if ((j -= 16384) < 128)            { srcp = b2; }
            else if ((j -= 128)   < 1280)           { srcp = Wl; }
            else    { j -= 1280;                      srcp = bl; }
            wf[i - N] = fl ? ((const float*)srcp)[j]
                           : gcn364_bf2f(((const unsigned short*)srcp)[j]);
        }
    }
}

// ---- exclusive scan of deg[N] -> off[N] (block-local) + dinvs/xf scaling ----
static __global__ void gcn364_scan1(const int* __restrict__ deg, int* __restrict__ off,
                                    int* __restrict__ partials, float4* __restrict__ xf4,
                                    int N) {
    __shared__ int sh[256];
    int t = threadIdx.x;
    int base = blockIdx.x * 1024 + t * 4;
    int v0 = (base + 0 < N) ? deg[base + 0] : 0;
    int v1 = (base + 1 < N) ? deg[base + 1] : 0;
    int v2 = (base + 2 < N) ? deg[base + 2] : 0;
    int v3 = (base + 3 < N) ? deg[base + 3] : 0;
    int s = v0 + v1 + v2 + v3;
    sh[t] = s;
    __syncthreads();
    for (int d = 1; d < 256; d <<= 1) {
        int val = (t >= d) ? sh[t - d] : 0;
        __syncthreads();
        sh[t] += val;
        __syncthreads();
    }
    int excl = sh[t] - s;
    int run = excl;
    if (base + 0 < N) off[base + 0] = run; run += v0;
    if (base + 1 < N) off[base + 1] = run; run += v1;
    if (base + 2 < N) off[base + 2] = run; run += v2;
    if (base + 3 < N) off[base + 3] = run;
    if (t == 255) partials[blockIdx.x] = sh[255];
    // dinvs + pre-scale xf by dinvs; dinvs rides in xf4.w
    int vv[4] = {v0, v1, v2, v3};
    #pragma unroll
    for (int k = 0; k < 4; k++) {
        int i = base + k;
        if (i < N) {
            float di = rsqrtf((float)vv[k] + 1.0f);
            float4 xv = xf4[i];
            xv.x *= di; xv.y *= di; xv.z *= di; xv.w = di;
            xf4[i] = xv;
        }
    }
}

// single block: exclusive scan of per-block partials
static __global__ void gcn364_scan2(int* __restrict__ partials, int nb) {
    __shared__ int sh[256];
    int t = threadIdx.x;
    int v = (t < nb) ? partials[t] : 0;
    sh[t] = v;
    __syncthreads();
    for (int d = 1; d < 256; d <<= 1) {
        int val = (t >= d) ? sh[t - d] : 0;
        __syncthreads();
        sh[t] += val;
        __syncthreads();
    }
    if (t < nb) partials[t] = sh[t] - v;   // exclusive
}

// XCD-affine filtered fill + layer-1 aggregation. Grid = slices x 8 regions.
// Matching edges: place in CSR bucket AND atomicAdd xf4[src].xyz into
// u4[dst] (region-local fp32 L2 atomics — one XCD owns each region's lines).
// Afterwards off[i] + partials[i>>10] == end offset of node i.
static __global__ void gcn364_fillagg(const int* __restrict__ src,
                                      const int* __restrict__ dst,
                                      int* __restrict__ off, const int* __restrict__ partials,
                                      int* __restrict__ esrc,
                                      const float4* __restrict__ xf4,
                                      float4* __restrict__ u4, int E, int N) {
    int r = blockIdx.x & 7;
    int s = blockIdx.x >> 3;
    int regSize = (N + 7) >> 3;
    int rlo = r * regSize;
    int rhi = rlo + regSize;
    int elo = s * FILL_CH;
    int ehi = elo + FILL_CH;
    if (ehi > E) ehi = E;
    for (int e = elo + threadIdx.x; e < ehi; e += 256) {
        int d = dst[e];
        if (d >= rlo && d < rhi) {
            int sv = src[e];
            int p = atomicAdd(&off[d], 1) + partials[d >> 10];
            esrc[p] = sv;
            float4 xs = xf4[sv];
            float* up = (float*)&u4[d];
            atomicAdd(up + 0, xs.x);
            atomicAdd(up + 1, xs.y);
            atomicAdd(up + 2, xs.z);
        }
    }
}

// finalize u4: u = di*(sum + x_i), .w = di  (xf4 pre-scaled, dinvs in .w)
static __global__ void gcn364_scaleu(const float4* __restrict__ xf4,
                                     float4* __restrict__ u4, int N) {
    int i = blockIdx.x * blockDim.x + threadIdx.x;
    if (i >= N) return;
    float4 xi = xf4[i];
    float di = xi.w;
    float4 ua = u4[i];
    u4[i] = make_float4(di * (ua.x + xi.x), di * (ua.y + xi.y), di * (ua.z + xi.z), di);
}

// per-edge layer-1 row recompute + accumulate (packed dual-fp32)
__device__ __forceinline__ void gcn364_edge(const float4 u,
                                            const gcn364_f2* wa2, const gcn364_f2* wb2,
                                            const gcn364_f2* wc2, const gcn364_f2* bb2,
                                            gcn364_f2* acc) {
    gcn364_f2 ux = {u.x, u.x}, uy = {u.y, u.y}, uz = {u.z, u.z}, uw = {u.w, u.w};
    gcn364_f2 zero = {0.f, 0.f};
    #pragma unroll
    for (int q = 0; q < 4; q++) {
        gcn364_f2 t = ux * wa2[q] + uy * wb2[q] + uz * wc2[q] + bb2[q];
        t = __builtin_elementwise_max(t, zero);
        acc[q] += uw * t;
    }
}

// Fused layer-2: per-edge on-the-fly layer-1 recompute + aggregation + GEMM +
// relu + mean-pool. MPB=16 nodes/block, 256 thr = 16 groups x 16 lanes,
// group-per-node (R8 tiling), packed dual-fp32 (R9 math).
#define MPB 16
static __global__ __launch_bounds__(256, 8) void gcn364_agg2pool(
        const int* __restrict__ esrc, const int* __restrict__ off,
        const int* __restrict__ partials, const float4* __restrict__ u4,
        const float* __restrict__ w1f, const float* __restrict__ b1f,
        const float* __restrict__ w2f, const float* __restrict__ b2f,
        const int* __restrict__ batch, float* __restrict__ pooled, int N) {
    __shared__ float vsh[MPB][H];
    int i0 = blockIdx.x * MPB;
    int tid = threadIdx.x;
    int wave = tid >> 6;
    int lane = tid & 63;
    int grp = lane >> 4;
    int sub = lane & 15;
    int node = wave * 4 + grp;
    int i = i0 + node;

    gcn364_f2 wa2[4], wb2[4], wc2[4], bb2[4];
    #pragma unroll
    for (int q = 0; q < 4; q++) {
        int f = sub * 8 + q * 2;
        wa2[q] = (gcn364_f2){w1f[f], w1f[f + 1]};
        wb2[q] = (gcn364_f2){w1f[H + f], w1f[H + f + 1]};
        wc2[q] = (gcn364_f2){w1f[2 * H + f], w1f[2 * H + f + 1]};
        bb2[q] = (gcn364_f2){b1f[f], b1f[f + 1]};
    }

    gcn364_f2 acc[4];
    acc[0] = acc[1] = acc[2] = acc[3] = (gcn364_f2){0.f, 0.f};
    float di = 0.f;
    if (i < N) {
        int p0 = (i == 0) ? 0 : off[i - 1] + partials[(i - 1) >> 10];
        int p1 = off[i] + partials[i >> 10];
        int p = p0;
        for (; p + 2 <= p1; p += 2) {
            float4 uA = u4[esrc[p]];
            float4 uB = u4[esrc[p + 1]];
            gcn364_edge(uA, wa2, wb2, wc2, bb2, acc);
            gcn364_edge(uB, wa2, wb2, wc2, bb2, acc);
        }
        if (p < p1) {
            float4 uA = u4[esrc[p]];
            gcn364_edge(uA, wa2, wb2, wc2, bb2, acc);
        }
        float4 uS = u4[i];   // self-loop
        gcn364_edge(uS, wa2, wb2, wc2, bb2, acc);
        di = uS.w;
    }
    *(float4*)&vsh[node][sub * 8 + 0] =
        make_float4(acc[0].x * di, acc[0].y * di, acc[1].x * di, acc[1].y * di);
    *(float4*)&vsh[node][sub * 8 + 4] =
        make_float4(acc[2].x * di, acc[2].y * di, acc[3].x * di, acc[3].y * di);
    __syncthreads();

    int f = tid & (H - 1);
    int half = tid >> 7;
    float bb = b2f[f];
    gcn364_f2 a2[8];
    #pragma unroll
    for (int n = 0; n < 8; n++) a2[n] = (gcn364_f2){0.f, 0.f};
    for (int k4 = 0; k4 < H / 4; k4++) {
        gcn364_f2 wlo = {w2f[(k4 * 4 + 0) * H + f], w2f[(k4 * 4 + 1) * H + f]};
        gcn364_f2 whi = {w2f[(k4 * 4 + 2) * H + f], w2f[(k4 * 4 + 3) * H + f]};
        #pragma unroll
        for (int n = 0; n < 8; n++) {
            float4 v = *(const float4*)&vsh[2 * n + half][k4 * 4];
            a2[n] += (gcn364_f2){v.x, v.y} * wlo + (gcn364_f2){v.z, v.w} * whi;
        }
    }

    float sum = 0.0f;
    int curg = -1;
    #pragma unroll
    for (int j = 0; j < 8; j++) {
        int ii = i0 + half + 2 * j;
        if (ii >= N) continue;
        float val = fmaxf(a2[j].x + a2[j].y + bb, 0.0f);
        int g = batch[ii];
        if (g != curg) {
            if (curg >= 0) atomicAdd(&pooled[curg * H + f], sum);
            curg = g;
            sum = 0.0f;
        }
        sum += val;
    }
    if (curg >= 0) atomicAdd(&pooled[curg * H + f], sum);
}

// out[g] = (pooled[g]/cnt_g) @ Wl + bl  -> detected dtype.
static __global__ void gcn364_final(const float* __restrict__ pooled,
                                    const int* __restrict__ batch,
                                    const float* __restrict__ wlf,
                                    const float* __restrict__ blf,
                                    const int* __restrict__ flag,
                                    void* __restrict__ out, int N, int G) {
    int g = blockIdx.x;
    int o = threadIdx.x;
    if (g >= G || o >= OUTF) return;
    int lo = 0, hi = N;
    while (lo < hi) { int m = (lo + hi) >> 1; if (batch[m] < g) lo = m + 1; else hi = m; }
    int a = lo;
    lo = 0; hi = N;
    while (lo < hi) { int m = (lo + hi) >> 1; if (batch[m] < g + 1) lo = m + 1; else hi = m; }
    float cn = (float)(lo - a);
    float inv = 1.0f / fmaxf(cn, 1.0f);
    float acc = 0.0f;
    for (int k = 0; k < H; k++)
        acc += pooled[g * H + k] * wlf[k * OUTF + o];
    float v = acc * inv + blf[o];
    if (*flag) ((float*)out)[g * OUTF + o] = v;
    else       ((unsigned short*)out)[g * OUTF + o] = gcn364_f2bf(v);
}

extern "C" void kernel_launch(void* const* d_in, const int* in_sizes, int n_in,
                              void* d_out, int out_size, void* d_ws, size_t ws_size,
                              hipStream_t stream) {
    const void* x  = d_in[0];
    const int* edge_index = (const int*)d_in[1];
    const int* batch      = (const int*)d_in[2];
    const void* W1 = d_in[3];
    const void* b1 = d_in[4];
    const void* W2 = d_in[5];
    const void* b2 = d_in[6];
    const void* Wl = d_in[7];
    const void* bl = d_in[8];

    const int N = in_sizes[0] / DIN;
    const int E = in_sizes[1] / 2;
    const int G = out_size / OUTF;
    const int* src = edge_index;
    const int* dst = edge_index + E;
    const int NB = (N + 1023) / 1024;   // scan blocks (must be <= 256)
    const int S = (E + FILL_CH - 1) / FILL_CH;

    // ---- workspace layout; u4+deg+pooled zeroed (contiguous at ws start) ----
    char* wsb = (char*)d_ws;
    float4* u4    = (float4*)wsb;                                 // N float4 (zeroed)
    int*   deg     = (int*)(u4 + N);                              // N        (zeroed)
    float* pooled  = (float*)(deg + N);                           // G*H      (zeroed)
    int*   off     = (int*)(pooled + (size_t)G * H);              // N
    int*   partials = off + N;                                    // 256
    int*   flag    = partials + 256;                              // 1
    size_t ofs = (((size_t)((char*)(flag + 1) - wsb)) + 15) & ~(size_t)15;
    float4* xf4 = (float4*)(wsb + ofs);                           // N float4
    float* wf   = (float*)(xf4 + N);                              // NWEIGHT
    int*   esrc = (int*)(wf + NWEIGHT);                           // E

    float* w1f = wf;
    float* b1f = w1f + 384;
    float* w2f = b1f + 128;
    float* b2f = w2f + 16384;
    float* wlf = b2f + 128;
    float* blf = wlf + 1280;

    hipMemsetAsync(d_ws, 0,
                   (size_t)N * 16 + (size_t)N * 4 + (size_t)G * H * 4, stream);

    gcn364_prep<<<S * 8, 256, 0, stream>>>(
        x, W1, b1, W2, b2, Wl, bl, flag, xf4, wf, dst, deg, N, E);
    gcn364_scan1<<<NB, 256, 0, stream>>>(deg, off, partials, xf4, N);
    gcn364_scan2<<<1, 256, 0, stream>>>(partials, NB);
    gcn364_fillagg<<<S * 8, 256, 0, stream>>>(
        src, dst, off, partials, esrc, xf4, u4, E, N);
    gcn364_scaleu<<<(N + 255) / 256, 256, 0, stream>>>(xf4, u4, N);
    gcn364_agg2pool<<<(N + MPB - 1) / MPB, 256, 0, stream>>>(
        esrc, off, partials, u4, w1f, b1f, w2f, b2f, batch, pooled, N);
    gcn364_final<<<G, 64, 0, stream>>>(pooled, batch, wlf, blf, flag, d_out, N, G);
}

// Round 13
// 529.303 us; speedup vs baseline: 1.0982x; 1.0982x over previous
//
#include <hip/hip_runtime.h>

// GCN: 2x GCNConv(+self-loop sym-norm) + ReLU, global mean pool, linear head.
// N=100000, E=1600000, G=100, D_IN=3, H=128, OUT=10.
//
// R12->R13: R12's fillagg WRITE=244MB == R6's 255MB despite region filtering
// -> fp32 atomicAdd is a CAS loop (no -munsafe-fp-atomics) that writes
// through regardless of XCD affinity. INT atomics ARE native+L2-cached (R11's
// filtered fill proved it). So: keep the fill+layer1-agg fusion but
// accumulate FIXED-POINT round(xf * 2^22) via int atomicAdd (bounded:
// |xf|<=~6, deg<=~60 -> |sum| < 2^30; error ~5e-6 on u, ~1e-5 at output vs
// 2.7e-3 threshold). scaleu converts int->float in place. All other kernels
// are the R11-proven versions.
//
// All kernels static + gcn364_ prefix (cross-.so symbol collisions caused the
// round-1 silent failure). Runtime dtype probe handles bf16/fp32 harness mode.

#define DIN 3
#define H 128
#define OUTF 10
#define NWEIGHT (384 + 128 + 16384 + 128 + 1280 + 10)  // W1,b1,W2,b2,Wl,bl
#define FILL_CH 2048
#define FXSCALE 4194304.0f        // 2^22
#define FXINV   2.38418579e-07f   // 2^-22

typedef float gcn364_f2 __attribute__((ext_vector_type(2)));

__device__ __forceinline__ float gcn364_bf2f(unsigned short u) {
    return __uint_as_float(((unsigned int)u) << 16);
}
__device__ __forceinline__ unsigned short gcn364_f2bf(float f) {
    unsigned int u = __float_as_uint(f);
    u += 0x7FFFu + ((u >> 16) & 1u);   // round-to-nearest-even
    return (unsigned short)(u >> 16);
}

// per-wave dtype probe over x's first 256 ushorts: 1 -> fp32, 0 -> bf16.
__device__ __forceinline__ int gcn364_probe(const unsigned short* __restrict__ xs16) {
    int lane = threadIdx.x & 63;
    int outl = 0;
    #pragma unroll
    for (int k = 0; k < 4; k++) {
        unsigned short u = xs16[lane * 4 + k];
        int e = (u >> 7) & 0xFF;
        outl += (e < 100 || e > 140) ? 1 : 0;
    }
    #pragma unroll
    for (int d = 1; d < 64; d <<= 1) outl += __shfl_xor(outl, d);
    return (outl > 32) ? 1 : 0;
}

// prep: XCD-affine filtered int deg count (grid = slices x 8 regions) +
// dtype conversion (low blocks convert x -> xf4, weights -> wf) + flag.
static __global__ void gcn364_prep(const void* __restrict__ x,
                                   const void* __restrict__ W1, const void* __restrict__ b1,
                                   const void* __restrict__ W2, const void* __restrict__ b2,
                                   const void* __restrict__ Wl, const void* __restrict__ bl,
                                   int* __restrict__ flag,
                                   float4* __restrict__ xf4, float* __restrict__ wf,
                                   const int* __restrict__ edst, int* __restrict__ deg,
                                   int N, int E) {
    int r = blockIdx.x & 7;
    int s = blockIdx.x >> 3;
    int regSize = (N + 7) >> 3;
    int rlo = r * regSize;
    int rhi = rlo + regSize;
    int elo = s * FILL_CH;
    int ehi = elo + FILL_CH;
    if (ehi > E) ehi = E;
    for (int e = elo + threadIdx.x; e < ehi; e += 256) {
        int d = edst[e];
        if (d >= rlo && d < rhi) atomicAdd(&deg[d], 1);
    }
    int i = blockIdx.x * blockDim.x + threadIdx.x;
    int total = N + NWEIGHT;
    if (blockIdx.x * 256 < total) {
        int fl = gcn364_probe((const unsigned short*)x);
        if (i == 0) *flag = fl;
        if (i < N) {
            float a, b, c;
            if (fl) {
                const float* xs = (const float*)x;
                a = xs[3 * i]; b = xs[3 * i + 1]; c = xs[3 * i + 2];
            } else {
                const unsigned short* xs = (const unsigned short*)x;
                a = gcn364_bf2f(xs[3 * i]);
                b = gcn364_bf2f(xs[3 * i + 1]);
                c = gcn364_bf2f(xs[3 * i + 2]);
            }
            xf4[i] = make_float4(a, b, c, 0.f);
        } else if (i < total) {
            int j = i - N;
            const void* srcp;
            if      (j < 384)                       { srcp = W1; }
            else if ((j -= 384)   < 128)            { srcp = b1; }
            else if ((j -= 128)   < 16384)          { srcp = W2; }
            else if ((j -= 16384) < 128)            { srcp = b2; }
            else if ((j -= 128)   < 1280)           { srcp = Wl; }
            else    { j -= 1280;                      srcp = bl; }
            wf[i - N] = fl ? ((const float*)srcp)[j]
                           : gcn364_bf2f(((const unsigned short*)srcp)[j]);
        }
    }
}

// ---- exclusive scan of deg[N] -> off[N] (block-local) + dinvs/xf scaling ----
static __global__ void gcn364_scan1(const int* __restrict__ deg, int* __restrict__ off,
                                    int* __restrict__ partials, float4* __restrict__ xf4,
                                    int N) {
    __shared__ int sh[256];
    int t = threadIdx.x;
    int base = blockIdx.x * 1024 + t * 4;
    int v0 = (base + 0 < N) ? deg[base + 0] : 0;
    int v1 = (base + 1 < N) ? deg[base + 1] : 0;
    int v2 = (base + 2 < N) ? deg[base + 2] : 0;
    int v3 = (base + 3 < N) ? deg[base + 3] : 0;
    int s = v0 + v1 + v2 + v3;
    sh[t] = s;
    __syncthreads();
    for (int d = 1; d < 256; d <<= 1) {
        int val = (t >= d) ? sh[t - d] : 0;
        __syncthreads();
        sh[t] += val;
        __syncthreads();
    }
    int excl = sh[t] - s;
    int run = excl;
    if (base + 0 < N) off[base + 0] = run; run += v0;
    if (base + 1 < N) off[base + 1] = run; run += v1;
    if (base + 2 < N) off[base + 2] = run; run += v2;
    if (base + 3 < N) off[base + 3] = run;
    if (t == 255) partials[blockIdx.x] = sh[255];
    // dinvs + pre-scale xf by dinvs; dinvs rides in xf4.w
    int vv[4] = {v0, v1, v2, v3};
    #pragma unroll
    for (int k = 0; k < 4; k++) {
        int i = base + k;
        if (i < N) {
            float di = rsqrtf((float)vv[k] + 1.0f);
            float4 xv = xf4[i];
            xv.x *= di; xv.y *= di; xv.z *= di; xv.w = di;
            xf4[i] = xv;
        }
    }
}

// single block: exclusive scan of per-block partials
static __global__ void gcn364_scan2(int* __restrict__ partials, int nb) {
    __shared__ int sh[256];
    int t = threadIdx.x;
    int v = (t < nb) ? partials[t] : 0;
    sh[t] = v;
    __syncthreads();
    for (int d = 1; d < 256; d <<= 1) {
        int val = (t >= d) ? sh[t - d] : 0;
        __syncthreads();
        sh[t] += val;
        __syncthreads();
    }
    if (t < nb) partials[t] = sh[t] - v;   // exclusive
}

// XCD-affine filtered fill + fixed-point layer-1 aggregation.
// Grid = slices x 8 regions. Matching edges: CSR bucket write + 3 INT
// atomicAdd of round(xf*2^22) into u4i[dst] (native, region-local, L2-cached
// — the pattern R11 validated on int cursor atomics).
// Afterwards off[i] + partials[i>>10] == end offset of node i.
static __global__ void gcn364_fillagg(const int* __restrict__ src,
                                      const int* __restrict__ dst,
                                      int* __restrict__ off, const int* __restrict__ partials,
                                      int* __restrict__ esrc,
                                      const float4* __restrict__ xf4,
                                      int* __restrict__ u4i, int E, int N) {
    int r = blockIdx.x & 7;
    int s = blockIdx.x >> 3;
    int regSize = (N + 7) >> 3;
    int rlo = r * regSize;
    int rhi = rlo + regSize;
    int elo = s * FILL_CH;
    int ehi = elo + FILL_CH;
    if (ehi > E) ehi = E;
    for (int e = elo + threadIdx.x; e < ehi; e += 256) {
        int d = dst[e];
        if (d >= rlo && d < rhi) {
            int sv = src[e];
            int p = atomicAdd(&off[d], 1) + partials[d >> 10];
            esrc[p] = sv;
            float4 xs = xf4[sv];
            int* up = u4i + 4 * d;
            atomicAdd(up + 0, __float2int_rn(xs.x * FXSCALE));
            atomicAdd(up + 1, __float2int_rn(xs.y * FXSCALE));
            atomicAdd(up + 2, __float2int_rn(xs.z * FXSCALE));
        }
    }
}

// finalize u4 in place: u = di*(sum_fx*2^-22 + x_i), .w = di
static __global__ void gcn364_scaleu(const float4* __restrict__ xf4,
                                     int* __restrict__ u4i, int N) {
    int i = blockIdx.x * blockDim.x + threadIdx.x;
    if (i >= N) return;
    float4 xi = xf4[i];
    float di = xi.w;
    int4 ua = *(const int4*)(u4i + 4 * i);
    float4 o = make_float4(di * ((float)ua.x * FXINV + xi.x),
                           di * ((float)ua.y * FXINV + xi.y),
                           di * ((float)ua.z * FXINV + xi.z), di);
    *(float4*)(u4i + 4 * i) = o;
}

// per-edge layer-1 row recompute + accumulate (packed dual-fp32)
__device__ __forceinline__ void gcn364_edge(const float4 u,
                                            const gcn364_f2* wa2, const gcn364_f2* wb2,
                                            const gcn364_f2* wc2, const gcn364_f2* bb2,
                                            gcn364_f2* acc) {
    gcn364_f2 ux = {u.x, u.x}, uy = {u.y, u.y}, uz = {u.z, u.z}, uw = {u.w, u.w};
    gcn364_f2 zero = {0.f, 0.f};
    #pragma unroll
    for (int q = 0; q < 4; q++) {
        gcn364_f2 t = ux * wa2[q] + uy * wb2[q] + uz * wc2[q] + bb2[q];
        t = __builtin_elementwise_max(t, zero);
        acc[q] += uw * t;
    }
}

// Fused layer-2: per-edge on-the-fly layer-1 recompute + aggregation + GEMM +
// relu + mean-pool. MPB=16 nodes/block, 256 thr = 16 groups x 16 lanes,
// group-per-node (R8 tiling), packed dual-fp32 (R9 math). [R11-proven]
#define MPB 16
static __global__ __launch_bounds__(256, 8) void gcn364_agg2pool(
        const int* __restrict__ esrc, const int* __restrict__ off,
        const int* __restrict__ partials, const float4* __restrict__ u4,
        const float* __restrict__ w1f, const float* __restrict__ b1f,
        const float* __restrict__ w2f, const float* __restrict__ b2f,
        const int* __restrict__ batch, float* __restrict__ pooled, int N) {
    __shared__ float vsh[MPB][H];
    int i0 = blockIdx.x * MPB;
    int tid = threadIdx.x;
    int wave = tid >> 6;
    int lane = tid & 63;
    int grp = lane >> 4;
    int sub = lane & 15;
    int node = wave * 4 + grp;
    int i = i0 + node;

    gcn364_f2 wa2[4], wb2[4], wc2[4], bb2[4];
    #pragma unroll
    for (int q = 0; q < 4; q++) {
        int f = sub * 8 + q * 2;
        wa2[q] = (gcn364_f2){w1f[f], w1f[f + 1]};
        wb2[q] = (gcn364_f2){w1f[H + f], w1f[H + f + 1]};
        wc2[q] = (gcn364_f2){w1f[2 * H + f], w1f[2 * H + f + 1]};
        bb2[q] = (gcn364_f2){b1f[f], b1f[f + 1]};
    }

    gcn364_f2 acc[4];
    acc[0] = acc[1] = acc[2] = acc[3] = (gcn364_f2){0.f, 0.f};
    float di = 0.f;
    if (i < N) {
        int p0 = (i == 0) ? 0 : off[i - 1] + partials[(i - 1) >> 10];
        int p1 = off[i] + partials[i >> 10];
        int p = p0;
        for (; p + 2 <= p1; p += 2) {
            float4 uA = u4[esrc[p]];
            float4 uB = u4[esrc[p + 1]];
            gcn364_edge(uA, wa2, wb2, wc2, bb2, acc);
            gcn364_edge(uB, wa2, wb2, wc2, bb2, acc);
        }
        if (p < p1) {
            float4 uA = u4[esrc[p]];
            gcn364_edge(uA, wa2, wb2, wc2, bb2, acc);
        }
        float4 uS = u4[i];   // self-loop
        gcn364_edge(uS, wa2, wb2, wc2, bb2, acc);
        di = uS.w;
    }
    *(float4*)&vsh[node][sub * 8 + 0] =
        make_float4(acc[0].x * di, acc[0].y * di, acc[1].x * di, acc[1].y * di);
    *(float4*)&vsh[node][sub * 8 + 4] =
        make_float4(acc[2].x * di, acc[2].y * di, acc[3].x * di, acc[3].y * di);
    __syncthreads();

    int f = tid & (H - 1);
    int half = tid >> 7;
    float bb = b2f[f];
    gcn364_f2 a2[8];
    #pragma unroll
    for (int n = 0; n < 8; n++) a2[n] = (gcn364_f2){0.f, 0.f};
    for (int k4 = 0; k4 < H / 4; k4++) {
        gcn364_f2 wlo = {w2f[(k4 * 4 + 0) * H + f], w2f[(k4 * 4 + 1) * H + f]};
        gcn364_f2 whi = {w2f[(k4 * 4 + 2) * H + f], w2f[(k4 * 4 + 3) * H + f]};
        #pragma unroll
        for (int n = 0; n < 8; n++) {
            float4 v = *(const float4*)&vsh[2 * n + half][k4 * 4];
            a2[n] += (gcn364_f2){v.x, v.y} * wlo + (gcn364_f2){v.z, v.w} * whi;
        }
    }

    float sum = 0.0f;
    int curg = -1;
    #pragma unroll
    for (int j = 0; j < 8; j++) {
        int ii = i0 + half + 2 * j;
        if (ii >= N) continue;
        float val = fmaxf(a2[j].x + a2[j].y + bb, 0.0f);
        int g = batch[ii];
        if (g != curg) {
            if (curg >= 0) atomicAdd(&pooled[curg * H + f], sum);
            curg = g;
            sum = 0.0f;
        }
        sum += val;
    }
    if (curg >= 0) atomicAdd(&pooled[curg * H + f], sum);
}

// out[g] = (pooled[g]/cnt_g) @ Wl + bl  -> detected dtype.
static __global__ void gcn364_final(const float* __restrict__ pooled,
                                    const int* __restrict__ batch,
                                    const float* __restrict__ wlf,
                                    const float* __restrict__ blf,
                                    const int* __restrict__ flag,
                                    void* __restrict__ out, int N, int G) {
    int g = blockIdx.x;
    int o = threadIdx.x;
    if (g >= G || o >= OUTF) return;
    int lo = 0, hi = N;
    while (lo < hi) { int m = (lo + hi) >> 1; if (batch[m] < g) lo = m + 1; else hi = m; }
    int a = lo;
    lo = 0; hi = N;
    while (lo < hi) { int m = (lo + hi) >> 1; if (batch[m] < g + 1) lo = m + 1; else hi = m; }
    float cn = (float)(lo - a);
    float inv = 1.0f / fmaxf(cn, 1.0f);
    float acc = 0.0f;
    for (int k = 0; k < H; k++)
        acc += pooled[g * H + k] * wlf[k * OUTF + o];
    float v = acc * inv + blf[o];
    if (*flag) ((float*)out)[g * OUTF + o] = v;
    else       ((unsigned short*)out)[g * OUTF + o] = gcn364_f2bf(v);
}

extern "C" void kernel_launch(void* const* d_in, const int* in_sizes, int n_in,
                              void* d_out, int out_size, void* d_ws, size_t ws_size,
                              hipStream_t stream) {
    const void* x  = d_in[0];
    const int* edge_index = (const int*)d_in[1];
    const int* batch      = (const int*)d_in[2];
    const void* W1 = d_in[3];
    const void* b1 = d_in[4];
    const void* W2 = d_in[5];
    const void* b2 = d_in[6];
    const void* Wl = d_in[7];
    const void* bl = d_in[8];

    const int N = in_sizes[0] / DIN;
    const int E = in_sizes[1] / 2;
    const int G = out_size / OUTF;
    const int* src = edge_index;
    const int* dst = edge_index + E;
    const int NB = (N + 1023) / 1024;   // scan blocks (must be <= 256)
    const int S = (E + FILL_CH - 1) / FILL_CH;

    // ---- workspace layout; u4i+deg+pooled zeroed (contiguous at ws start) ----
    char* wsb = (char*)d_ws;
    int*   u4i     = (int*)wsb;                                   // 4N ints (zeroed; becomes float4 u4)
    int*   deg     = u4i + (size_t)4 * N;                         // N        (zeroed)
    float* pooled  = (float*)(deg + N);                           // G*H      (zeroed)
    int*   off     = (int*)(pooled + (size_t)G * H);              // N
    int*   partials = off + N;                                    // 256
    int*   flag    = partials + 256;                              // 1
    size_t ofs = (((size_t)((char*)(flag + 1) - wsb)) + 15) & ~(size_t)15;
    float4* xf4 = (float4*)(wsb + ofs);                           // N float4
    float* wf   = (float*)(xf4 + N);                              // NWEIGHT
    int*   esrc = (int*)(wf + NWEIGHT);                           // E

    float* w1f = wf;
    float* b1f = w1f + 384;
    float* w2f = b1f + 128;
    float* b2f = w2f + 16384;
    float* wlf = b2f + 128;
    float* blf = wlf + 1280;

    hipMemsetAsync(d_ws, 0,
                   (size_t)N * 16 + (size_t)N * 4 + (size_t)G * H * 4, stream);

    gcn364_prep<<<S * 8, 256, 0, stream>>>(
        x, W1, b1, W2, b2, Wl, bl, flag, xf4, wf, dst, deg, N, E);
    gcn364_scan1<<<NB, 256, 0, stream>>>(deg, off, partials, xf4, N);
    gcn364_scan2<<<1, 256, 0, stream>>>(partials, NB);
    gcn364_fillagg<<<S * 8, 256, 0, stream>>>(
        src, dst, off, partials, esrc, xf4, u4i, E, N);
    gcn364_scaleu<<<(N + 255) / 256, 256, 0, stream>>>(xf4, u4i, N);
    gcn364_agg2pool<<<(N + MPB - 1) / MPB, 256, 0, stream>>>(
        esrc, off, partials, (const float4*)u4i, w1f, b1f, w2f, b2f, batch, pooled, N);
    gcn364_final<<<G, 64, 0, stream>>>(pooled, batch, wlf, blf, flag, d_out, N, G);
}

// Round 14
// 373.095 us; speedup vs baseline: 1.5580x; 1.4187x over previous
//
#include <hip/hip_runtime.h>

// GCN: 2x GCNConv(+self-loop sym-norm) + ReLU, global mean pool, linear head.
// N=100000, E=1600000, G=100, D_IN=3, H=128, OUT=10.
//
// R13->R14: revert to the R11-proven pipeline. Lesson from R6/R12/R13:
// device-scope global atomics execute memory-side (past the per-XCD L2) —
// every atomic crosses the fabric (~64B write) regardless of dtype or XCD
// affinity (int WRITE=245MB == fp32's 244MB). So: exactly 1 atomic/edge
// (CSR cursor), aggregation via plain stores + L2 gathers (aggu pass).
// New in R14: (1) agg2pool groups own 2 CONSECUTIVE nodes (MPB=32, 16KB
// LDS) -> divergence cost = max(sum-of-2-degs)/2, ~10% better balance;
// (2) 4-deep edge load pipeline in phase A to hide L2 latency;
// (3) FILL_CH 2048->4096 (halve block count in prep/fill).
//
// All kernels static + gcn364_ prefix (cross-.so symbol collisions caused the
// round-1 silent failure). Runtime dtype probe handles bf16/fp32 harness mode.

#define DIN 3
#define H 128
#define OUTF 10
#define NWEIGHT (384 + 128 + 16384 + 128 + 1280 + 10)  // W1,b1,W2,b2,Wl,bl
#define FILL_CH 4096

typedef float gcn364_f2 __attribute__((ext_vector_type(2)));

__device__ __forceinline__ float gcn364_bf2f(unsigned short u) {
    return __uint_as_float(((unsigned int)u) << 16);
}
__device__ __forceinline__ unsigned short gcn364_f2bf(float f) {
    unsigned int u = __float_as_uint(f);
    u += 0x7FFFu + ((u >> 16) & 1u);   // round-to-nearest-even
    return (unsigned short)(u >> 16);
}

// per-wave dtype probe over x's first 256 ushorts: 1 -> fp32, 0 -> bf16.
__device__ __forceinline__ int gcn364_probe(const unsigned short* __restrict__ xs16) {
    int lane = threadIdx.x & 63;
    int outl = 0;
    #pragma unroll
    for (int k = 0; k < 4; k++) {
        unsigned short u = xs16[lane * 4 + k];
        int e = (u >> 7) & 0xFF;
        outl += (e < 100 || e > 140) ? 1 : 0;
    }
    #pragma unroll
    for (int d = 1; d < 64; d <<= 1) outl += __shfl_xor(outl, d);
    return (outl > 32) ? 1 : 0;
}

// prep: XCD-affine filtered deg count (grid = slices x 8 regions) + dtype
// conversion (low blocks convert x -> xf4, weights -> wf) + flag publish.
static __global__ void gcn364_prep(const void* __restrict__ x,
                                   const void* __restrict__ W1, const void* __restrict__ b1,
                                   const void* __restrict__ W2, const void* __restrict__ b2,
                                   const void* __restrict__ Wl, const void* __restrict__ bl,
                                   int* __restrict__ flag,
                                   float4* __restrict__ xf4, float* __restrict__ wf,
                                   const int* __restrict__ edst, int* __restrict__ deg,
                                   int N, int E) {
    int r = blockIdx.x & 7;
    int s = blockIdx.x >> 3;
    int regSize = (N + 7) >> 3;
    int rlo = r * regSize;
    int rhi = rlo + regSize;
    int elo = s * FILL_CH;
    int ehi = elo + FILL_CH;
    if (ehi > E) ehi = E;
    for (int e = elo + threadIdx.x; e < ehi; e += 256) {
        int d = edst[e];
        if (d >= rlo && d < rhi) atomicAdd(&deg[d], 1);
    }
    int i = blockIdx.x * blockDim.x + threadIdx.x;
    int total = N + NWEIGHT;
    if (blockIdx.x * 256 < total) {
        int fl = gcn364_probe((const unsigned short*)x);
        if (i == 0) *flag = fl;
        if (i < N) {
            float a, b, c;
            if (fl) {
                const float* xs = (const float*)x;
                a = xs[3 * i]; b = xs[3 * i + 1]; c = xs[3 * i + 2];
            } else {
                const unsigned short* xs = (const unsigned short*)x;
                a = gcn364_bf2f(xs[3 * i]);
                b = gcn364_bf2f(xs[3 * i + 1]);
                c = gcn364_bf2f(xs[3 * i + 2]);
            }
            xf4[i] = make_float4(a, b, c, 0.f);
        } else if (i < total) {
            int j = i - N;
            const void* srcp;
            if      (j < 384)                       { srcp = W1; }
            else if ((j -= 384)   < 128)            { srcp = b1; }
            else if ((j -= 128)   < 16384)          { srcp = W2; }
            else if ((j -= 16384) < 128)            { srcp = b2; }
            else if ((j -= 128)   < 1280)           { srcp = Wl; }
            else    { j -= 1280;                      srcp = bl; }
            wf[i - N] = fl ? ((const float*)srcp)[j]
                           : gcn364_bf2f(((const unsigned short*)srcp)[j]);
        }
    }
}

// ---- exclusive scan of deg[N] -> off[N] (block-local) + dinvs/xf scaling ----
static __global__ void gcn364_scan1(const int* __restrict__ deg, int* __restrict__ off,
                                    int* __restrict__ partials, float4* __restrict__ xf4,
                                    int N) {
    __shared__ int sh[256];
    int t = threadIdx.x;
    int base = blockIdx.x * 1024 + t * 4;
    int v0 = (base + 0 < N) ? deg[base + 0] : 0;
    int v1 = (base + 1 < N) ? deg[base + 1] : 0;
    int v2 = (base + 2 < N) ? deg[base + 2] : 0;
    int v3 = (base + 3 < N) ? deg[base + 3] : 0;
    int s = v0 + v1 + v2 + v3;
    sh[t] = s;
    __syncthreads();
    for (int d = 1; d < 256; d <<= 1) {
        int val = (t >= d) ? sh[t - d] : 0;
        __syncthreads();
        sh[t] += val;
        __syncthreads();
    }
    int excl = sh[t] - s;
    int run = excl;
    if (base + 0 < N) off[base + 0] = run; run += v0;
    if (base + 1 < N) off[base + 1] = run; run += v1;
    if (base + 2 < N) off[base + 2] = run; run += v2;
    if (base + 3 < N) off[base + 3] = run;
    if (t == 255) partials[blockIdx.x] = sh[255];
    // dinvs + pre-scale xf by dinvs; dinvs rides in xf4.w
    int vv[4] = {v0, v1, v2, v3};
    #pragma unroll
    for (int k = 0; k < 4; k++) {
        int i = base + k;
        if (i < N) {
            float di = rsqrtf((float)vv[k] + 1.0f);
            float4 xv = xf4[i];
            xv.x *= di; xv.y *= di; xv.z *= di; xv.w = di;
            xf4[i] = xv;
        }
    }
}

// single block: exclusive scan of per-block partials
static __global__ void gcn364_scan2(int* __restrict__ partials, int nb) {
    __shared__ int sh[256];
    int t = threadIdx.x;
    int v = (t < nb) ? partials[t] : 0;
    sh[t] = v;
    __syncthreads();
    for (int d = 1; d < 256; d <<= 1) {
        int val = (t >= d) ? sh[t - d] : 0;
        __syncthreads();
        sh[t] += val;
        __syncthreads();
    }
    if (t < nb) partials[t] = sh[t] - v;   // exclusive
}

// XCD-affine filtered bucket fill. Grid = slices x 8 regions. ONE atomic per
// edge (cursor); esrc stores are region-local plain writes (R11-proven).
// Afterwards off[i] + partials[i>>10] == end offset of node i.
static __global__ void gcn364_fill(const int* __restrict__ src, const int* __restrict__ dst,
                                   int* __restrict__ off, const int* __restrict__ partials,
                                   int* __restrict__ esrc, int E, int N) {
    int r = blockIdx.x & 7;
    int s = blockIdx.x >> 3;
    int regSize = (N + 7) >> 3;
    int rlo = r * regSize;
    int rhi = rlo + regSize;
    int elo = s * FILL_CH;
    int ehi = elo + FILL_CH;
    if (ehi > E) ehi = E;
    for (int e = elo + threadIdx.x; e < ehi; e += 256) {
        int d = dst[e];
        if (d >= rlo && d < rhi) {
            int p = atomicAdd(&off[d], 1) + partials[d >> 10];
            esrc[p] = src[e];
        }
    }
}

// Layer-1 aggregation -> u4 records. 16 lanes per node, 4 nodes per wave.
// xf4 pre-scaled by dinvs (dinvs in .w). One float4 load per edge.
static __global__ void gcn364_aggu(const int* __restrict__ esrc,
                                   const int* __restrict__ off,
                                   const int* __restrict__ partials,
                                   const float4* __restrict__ xf4,
                                   float4* __restrict__ u4, int N) {
    int lane = threadIdx.x & 63;
    int wv = threadIdx.x >> 6;
    int grp = lane >> 4;
    int sub = lane & 15;
    int i = (blockIdx.x * 4 + wv) * 4 + grp;

    float a0 = 0.f, a1 = 0.f, a2 = 0.f;
    if (i < N) {
        int p0 = (i == 0) ? 0 : off[i - 1] + partials[(i - 1) >> 10];
        int p1 = off[i] + partials[i >> 10];
        for (int p = p0 + sub; p < p1; p += 16) {
            float4 sv = xf4[esrc[p]];
            a0 += sv.x; a1 += sv.y; a2 += sv.z;
        }
    }
    for (int d = 1; d < 16; d <<= 1) {
        a0 += __shfl_xor(a0, d);
        a1 += __shfl_xor(a1, d);
        a2 += __shfl_xor(a2, d);
    }
    if (i < N && sub == 0) {
        float4 xi = xf4[i];
        float di = xi.w;
        u4[i] = make_float4(di * (a0 + xi.x), di * (a1 + xi.y), di * (a2 + xi.z), di);
    }
}

// per-edge layer-1 row recompute + accumulate (packed dual-fp32)
__device__ __forceinline__ void gcn364_edge(const float4 u,
                                            const gcn364_f2* wa2, const gcn364_f2* wb2,
                                            const gcn364_f2* wc2, const gcn364_f2* bb2,
                                            gcn364_f2* acc) {
    gcn364_f2 ux = {u.x, u.x}, uy = {u.y, u.y}, uz = {u.z, u.z}, uw = {u.w, u.w};
    gcn364_f2 zero = {0.f, 0.f};
    #pragma unroll
    for (int q = 0; q < 4; q++) {
        gcn364_f2 t = ux * wa2[q] + uy * wb2[q] + uz * wc2[q] + bb2[q];
        t = __builtin_elementwise_max(t, zero);
        acc[q] += uw * t;
    }
}

// Fused layer-2: per-edge on-the-fly layer-1 recompute + aggregation + GEMM +
// relu + mean-pool. MPB=32 nodes/block, 256 thr = 16 groups x 16 lanes.
// Each group owns 2 CONSECUTIVE nodes (balance: sum-of-2-degrees), 4-deep
// edge load pipeline hides L2 latency. Phase B: 2 chunks of 16 nodes,
// packed dual-fp32 GEMM, grouped pooled atomics (batch sorted).
#define MPB 32
static __global__ __launch_bounds__(256, 8) void gcn364_agg2pool(
        const int* __restrict__ esrc, const int* __restrict__ off,
        const int* __restrict__ partials, const float4* __restrict__ u4,
        const float* __restrict__ w1f, const float* __restrict__ b1f,
        const float* __restrict__ w2f, const float* __restrict__ b2f,
        const int* __restrict__ batch, float* __restrict__ pooled, int N) {
    __shared__ float vsh[MPB][H];
    int i0 = blockIdx.x * MPB;
    int tid = threadIdx.x;
    int wave = tid >> 6;
    int lane = tid & 63;
    int grp = lane >> 4;
    int sub = lane & 15;
    int gq = wave * 4 + grp;          // 0..15; owns nodes i0+2gq, i0+2gq+1

    gcn364_f2 wa2[4], wb2[4], wc2[4], bb2[4];
    #pragma unroll
    for (int q = 0; q < 4; q++) {
        int f = sub * 8 + q * 2;
        wa2[q] = (gcn364_f2){w1f[f], w1f[f + 1]};
        wb2[q] = (gcn364_f2){w1f[H + f], w1f[H + f + 1]};
        wc2[q] = (gcn364_f2){w1f[2 * H + f], w1f[2 * H + f + 1]};
        bb2[q] = (gcn364_f2){b1f[f], b1f[f + 1]};
    }

    #pragma unroll
    for (int c = 0; c < 2; c++) {
        int i = i0 + gq * 2 + c;
        gcn364_f2 acc[4];
        acc[0] = acc[1] = acc[2] = acc[3] = (gcn364_f2){0.f, 0.f};
        float di = 0.f;
        if (i < N) {
            int p0 = (i == 0) ? 0 : off[i - 1] + partials[(i - 1) >> 10];
            int p1 = off[i] + partials[i >> 10];
            int p = p0;
            for (; p + 4 <= p1; p += 4) {
                int s0 = esrc[p], s1 = esrc[p + 1], s2 = esrc[p + 2], s3 = esrc[p + 3];
                float4 uA = u4[s0];
                float4 uB = u4[s1];
                float4 uC = u4[s2];
                float4 uD = u4[s3];
                gcn364_edge(uA, wa2, wb2, wc2, bb2, acc);
                gcn364_edge(uB, wa2, wb2, wc2, bb2, acc);
                gcn364_edge(uC, wa2, wb2, wc2, bb2, acc);
                gcn364_edge(uD, wa2, wb2, wc2, bb2, acc);
            }
            for (; p < p1; p++) {
                float4 uA = u4[esrc[p]];
                gcn364_edge(uA, wa2, wb2, wc2, bb2, acc);
            }
            float4 uS = u4[i];   // self-loop
            gcn364_edge(uS, wa2, wb2, wc2, bb2, acc);
            di = uS.w;
        }
        *(float4*)&vsh[gq * 2 + c][sub * 8 + 0] =
            make_float4(acc[0].x * di, acc[0].y * di, acc[1].x * di, acc[1].y * di);
        *(float4*)&vsh[gq * 2 + c][sub * 8 + 4] =
            make_float4(acc[2].x * di, acc[2].y * di, acc[3].x * di, acc[3].y * di);
    }
    __syncthreads();

    int f = tid & (H - 1);
    int half = tid >> 7;
    float bb = b2f[f];
    #pragma unroll
    for (int t = 0; t < 2; t++) {
        gcn364_f2 a2[8];
        #pragma unroll
        for (int n = 0; n < 8; n++) a2[n] = (gcn364_f2){0.f, 0.f};
        for (int k4 = 0; k4 < H / 4; k4++) {
            gcn364_f2 wlo = {w2f[(k4 * 4 + 0) * H + f], w2f[(k4 * 4 + 1) * H + f]};
            gcn364_f2 whi = {w2f[(k4 * 4 + 2) * H + f], w2f[(k4 * 4 + 3) * H + f]};
            #pragma unroll
            for (int n = 0; n < 8; n++) {
                float4 v = *(const float4*)&vsh[t * 16 + 2 * n + half][k4 * 4];
                a2[n] += (gcn364_f2){v.x, v.y} * wlo + (gcn364_f2){v.z, v.w} * whi;
            }
        }
        float sum = 0.0f;
        int curg = -1;
        #pragma unroll
        for (int j = 0; j < 8; j++) {
            int ii = i0 + t * 16 + half + 2 * j;
            if (ii >= N) continue;
            float val = fmaxf(a2[j].x + a2[j].y + bb, 0.0f);
            int g = batch[ii];
            if (g != curg) {
                if (curg >= 0) atomicAdd(&pooled[curg * H + f], sum);
                curg = g;
                sum = 0.0f;
            }
            sum += val;
        }
        if (curg >= 0) atomicAdd(&pooled[curg * H + f], sum);
    }
}

// out[g] = (pooled[g]/cnt_g) @ Wl + bl  -> detected dtype.
static __global__ void gcn364_final(const float* __restrict__ pooled,
                                    const int* __restrict__ batch,
                                    const float* __restrict__ wlf,
                                    const float* __restrict__ blf,
                                    const int* __restrict__ flag,
                                    void* __restrict__ out, int N, int G) {
    int g = blockIdx.x;
    int o = threadIdx.x;
    if (g >= G || o >= OUTF) return;
    int lo = 0, hi = N;
    while (lo < hi) { int m = (lo + hi) >> 1; if (batch[m] < g) lo = m + 1; else hi = m; }
    int a = lo;
    lo = 0; hi = N;
    while (lo < hi) { int m = (lo + hi) >> 1; if (batch[m] < g + 1) lo = m + 1; else hi = m; }
    float cn = (float)(lo - a);
    float inv = 1.0f / fmaxf(cn, 1.0f);
    float acc = 0.0f;
    for (int k = 0; k < H; k++)
        acc += pooled[g * H + k] * wlf[k * OUTF + o];
    float v = acc * inv + blf[o];
    if (*flag) ((float*)out)[g * OUTF + o] = v;
    else       ((unsigned short*)out)[g * OUTF + o] = gcn364_f2bf(v);
}

extern "C" void kernel_launch(void* const* d_in, const int* in_sizes, int n_in,
                              void* d_out, int out_size, void* d_ws, size_t ws_size,
                              hipStream_t stream) {
    const void* x  = d_in[0];
    const int* edge_index = (const int*)d_in[1];
    const int* batch      = (const int*)d_in[2];
    const void* W1 = d_in[3];
    const void* b1 = d_in[4];
    const void* W2 = d_in[5];
    const void* b2 = d_in[6];
    const void* Wl = d_in[7];
    const void* bl = d_in[8];

    const int N = in_sizes[0] / DIN;
    const int E = in_sizes[1] / 2;
    const int G = out_size / OUTF;
    const int* src = edge_index;
    const int* dst = edge_index + E;
    const int NB = (N + 1023) / 1024;   // scan blocks (must be <= 256)
    const int S = (E + FILL_CH - 1) / FILL_CH;

    // ---- workspace layout; deg+pooled zeroed (contiguous at ws start) ----
    char* wsb = (char*)d_ws;
    int*   deg      = (int*)wsb;                                  // N      (zeroed)
    float* pooled   = (float*)(deg + N);                          // G*H    (zeroed)
    int*   off      = (int*)(pooled + (size_t)G * H);             // N
    int*   partials = off + N;                                    // 256
    int*   flag     = partials + 256;                             // 1
    size_t ofs = (((size_t)((char*)(flag + 1) - wsb)) + 15) & ~(size_t)15;
    float4* xf4 = (float4*)(wsb + ofs);                           // N float4
    float4* u4  = xf4 + N;                                        // N float4
    float* wf   = (float*)(u4 + N);                               // NWEIGHT
    int*   esrc = (int*)(wf + NWEIGHT);                           // E

    float* w1f = wf;
    float* b1f = w1f + 384;
    float* w2f = b1f + 128;
    float* b2f = w2f + 16384;
    float* wlf = b2f + 128;
    float* blf = wlf + 1280;

    hipMemsetAsync(d_ws, 0, ((size_t)N + (size_t)G * H) * 4, stream);

    gcn364_prep<<<S * 8, 256, 0, stream>>>(
        x, W1, b1, W2, b2, Wl, bl, flag, xf4, wf, dst, deg, N, E);
    gcn364_scan1<<<NB, 256, 0, stream>>>(deg, off, partials, xf4, N);
    gcn364_scan2<<<1, 256, 0, stream>>>(partials, NB);
    gcn364_fill<<<S * 8, 256, 0, stream>>>(src, dst, off, partials, esrc, E, N);
    gcn364_aggu<<<(N + 15) / 16, 256, 0, stream>>>(esrc, off, partials, xf4, u4, N);
    gcn364_agg2pool<<<(N + MPB - 1) / MPB, 256, 0, stream>>>(
        esrc, off, partials, u4, w1f, b1f, w2f, b2f, batch, pooled, N);
    gcn364_final<<<G, 64, 0, stream>>>(pooled, batch, wlf, blf, flag, d_out, N, G);
}

// Round 15
// 302.683 us; speedup vs baseline: 1.9205x; 1.2326x over previous
//
#include <hip/hip_runtime.h>

// GCN: 2x GCNConv(+self-loop sym-norm) + ReLU, global mean pool, linear head.
// N=100000, E=1600000, G=100, D_IN=3, H=128, OUT=10.
//
// R14->R15: (1) agg2pool reverted to R11-exact (MPB=16, group-per-node,
// 2-deep; R14's MPB=32+4-deep spilled at the 8-wave VGPR cap: WRITE 6->49MB).
// (2) CSR build rebuilt with ZERO global atomics (R6/R12/R13 showed
// device-scope atomics are memory-side ~64B fabric writes each; prep+fill's
// 3.2M atomics were the tail floor):
//   histconv: per-slice (8192 edges) LDS histogram over 196 regions
//             (512 nodes) + dtype conversion.
//   scanH:    1 block: per-(slice,region) bases + regionBase (region-major).
//   partition: LDS cursors from bases -> epack=(dlocal<<17)|src, plain stores.
//   build:    1 block/region: LDS deg hist -> LDS scan -> absolute off[],
//             LDS-cursor esrc placement, dinvs+xf scaling (deg block-local).
// Consumers use absolute off[] (partials indirection gone).
//
// All kernels static + gcn364_ prefix (cross-.so symbol collisions caused the
// round-1 silent failure). Runtime dtype probe handles bf16/fp32 harness mode.

#define DIN 3
#define H 128
#define OUTF 10
#define NWEIGHT (384 + 128 + 16384 + 128 + 1280 + 10)  // W1,b1,W2,b2,Wl,bl
#define ECH 8192            // edges per slice
#define RGSH 9              // region = 512 nodes
#define RGSIZE 512

typedef float gcn364_f2 __attribute__((ext_vector_type(2)));

__device__ __forceinline__ float gcn364_bf2f(unsigned short u) {
    return __uint_as_float(((unsigned int)u) << 16);
}
__device__ __forceinline__ unsigned short gcn364_f2bf(float f) {
    unsigned int u = __float_as_uint(f);
    u += 0x7FFFu + ((u >> 16) & 1u);   // round-to-nearest-even
    return (unsigned short)(u >> 16);
}

// per-wave dtype probe over x's first 256 ushorts: 1 -> fp32, 0 -> bf16.
__device__ __forceinline__ int gcn364_probe(const unsigned short* __restrict__ xs16) {
    int lane = threadIdx.x & 63;
    int outl = 0;
    #pragma unroll
    for (int k = 0; k < 4; k++) {
        unsigned short u = xs16[lane * 4 + k];
        int e = (u >> 7) & 0xFF;
        outl += (e < 100 || e > 140) ? 1 : 0;
    }
    #pragma unroll
    for (int d = 1; d < 64; d <<= 1) outl += __shfl_xor(outl, d);
    return (outl > 32) ? 1 : 0;
}

// histconv: blocks < S build the per-slice region histogram (LDS, plain
// global store); all blocks also convert x -> xf4 (unscaled) / weights -> wf.
static __global__ void gcn364_histconv(const void* __restrict__ x,
                                       const void* __restrict__ W1, const void* __restrict__ b1,
                                       const void* __restrict__ W2, const void* __restrict__ b2,
                                       const void* __restrict__ Wl, const void* __restrict__ bl,
                                       int* __restrict__ flag,
                                       float4* __restrict__ xf4, float* __restrict__ wf,
                                       const int* __restrict__ edst,
                                       int* __restrict__ hist,
                                       int N, int E, int S, int RG) {
    __shared__ int h[256];
    if (blockIdx.x < (unsigned)S) {
        h[threadIdx.x] = 0;
        __syncthreads();
        int elo = blockIdx.x * ECH;
        int ehi = elo + ECH; if (ehi > E) ehi = E;
        for (int e = elo + threadIdx.x; e < ehi; e += 256)
            atomicAdd(&h[edst[e] >> RGSH], 1);
        __syncthreads();
        if (threadIdx.x < RG) hist[blockIdx.x * RG + threadIdx.x] = h[threadIdx.x];
    }
    int i = blockIdx.x * blockDim.x + threadIdx.x;
    int total = N + NWEIGHT;
    if ((int)blockIdx.x * 256 < total) {
        int fl = gcn364_probe((const unsigned short*)x);
        if (i == 0) *flag = fl;
        if (i < N) {
            float a, b, c;
            if (fl) {
                const float* xs = (const float*)x;
                a = xs[3 * i]; b = xs[3 * i + 1]; c = xs[3 * i + 2];
            } else {
                const unsigned short* xs = (const unsigned short*)x;
                a = gcn364_bf2f(xs[3 * i]);
                b = gcn364_bf2f(xs[3 * i + 1]);
                c = gcn364_bf2f(xs[3 * i + 2]);
            }
            xf4[i] = make_float4(a, b, c, 0.f);
        } else if (i < total) {
            int j = i - N;
            const void* srcp;
            if      (j < 384)                       { srcp = W1; }
            else if ((j -= 384)   < 128)            { srcp = b1; }
            else if ((j -= 128)   < 16384)          { srcp = W2; }
            else if ((j -= 16384) < 128)            { srcp = b2; }
            else if ((j -= 128)   < 1280)           { srcp = Wl; }
            else    { j -= 1280;                      srcp = bl; }
            wf[i - N] = fl ? ((const float*)srcp)[j]
                           : gcn364_bf2f(((const unsigned short*)srcp)[j]);
        }
    }
}

// scanH (1 block): hist[s][r] -> per-(slice,region) LOCAL prefix (within
// region r across slices); regionBase[r] = exclusive scan of region totals;
// regionBase[RG] = E. Partition seeds cursors with hist + regionBase.
static __global__ void gcn364_scanH(int* __restrict__ hist,
                                    int* __restrict__ regionBase,
                                    int S, int RG, int E) {
    int r = threadIdx.x;
    int tot = 0;
    if (r < RG) {
        for (int s = 0; s < S; s++) {
            int idx = s * RG + r;
            int c = hist[idx];
            hist[idx] = tot;       // local prefix within region r
            tot += c;
        }
    }
    __shared__ int sh[256];
    sh[threadIdx.x] = (r < RG) ? tot : 0;
    __syncthreads();
    for (int d = 1; d < 256; d <<= 1) {
        int val = (threadIdx.x >= d) ? sh[threadIdx.x - d] : 0;
        __syncthreads();
        sh[threadIdx.x] += val;
        __syncthreads();
    }
    if (r < RG) regionBase[r] = sh[r] - tot;   // exclusive
    if (threadIdx.x == 0) regionBase[RG] = E;
}

// partition: slice s scatters its edges into region-major epack order using
// LDS cursors seeded from hist+regionBase. Plain stores only.
// epack = (dlocal << 17) | src   (src < 2^17, dlocal < 512)
static __global__ void gcn364_partition(const int* __restrict__ src,
                                        const int* __restrict__ dst,
                                        const int* __restrict__ hist,
                                        const int* __restrict__ regionBase,
                                        int* __restrict__ epack,
                                        int E, int RG) {
    __shared__ int cur[256];
    int s = blockIdx.x;
    if (threadIdx.x < RG)
        cur[threadIdx.x] = hist[s * RG + threadIdx.x] + regionBase[threadIdx.x];
    __syncthreads();
    int elo = s * ECH;
    int ehi = elo + ECH; if (ehi > E) ehi = E;
    for (int e = elo + threadIdx.x; e < ehi; e += 256) {
        int d = dst[e];
        int sv = src[e];
        int p = atomicAdd(&cur[d >> RGSH], 1);
        epack[p] = ((d & (RGSIZE - 1)) << 17) | sv;
    }
}

// build: one block per region. LDS deg hist over the region's contiguous
// epack run -> LDS scan -> absolute off[] (inclusive ends) -> LDS-cursor
// esrc placement. Also dinvs + xf4 scaling for the region's nodes.
static __global__ void gcn364_build(const int* __restrict__ epack,
                                    const int* __restrict__ regionBase,
                                    int* __restrict__ off,
                                    int* __restrict__ esrc,
                                    float4* __restrict__ xf4,
                                    int N) {
    __shared__ int sdeg[RGSIZE];
    __shared__ int stmp[256];
    int r = blockIdx.x;
    int nlo = r << RGSH;
    int nn = N - nlo; if (nn > RGSIZE) nn = RGSIZE;
    int e0 = regionBase[r];
    int e1 = regionBase[r + 1];
    int t = threadIdx.x;

    sdeg[t] = 0; sdeg[t + 256] = 0;
    __syncthreads();
    for (int p = e0 + t; p < e1; p += 256)
        atomicAdd(&sdeg[epack[p] >> 17], 1);
    __syncthreads();

    int a0 = sdeg[2 * t];
    int a1 = sdeg[2 * t + 1];
    int psum = a0 + a1;
    stmp[t] = psum;
    __syncthreads();
    for (int d = 1; d < 256; d <<= 1) {
        int val = (t >= d) ? stmp[t - d] : 0;
        __syncthreads();
        stmp[t] += val;
        __syncthreads();
    }
    int excl = stmp[t] - psum;

    // absolute inclusive end offsets
    if (2 * t < nn)     off[nlo + 2 * t]     = e0 + excl + a0;
    if (2 * t + 1 < nn) off[nlo + 2 * t + 1] = e0 + excl + a0 + a1;
    // dinvs + pre-scale xf (deg known in-register)
    if (2 * t < nn) {
        float di = rsqrtf((float)a0 + 1.0f);
        float4 xv = xf4[nlo + 2 * t];
        xv.x *= di; xv.y *= di; xv.z *= di; xv.w = di;
        xf4[nlo + 2 * t] = xv;
    }
    if (2 * t + 1 < nn) {
        float di = rsqrtf((float)a1 + 1.0f);
        float4 xv = xf4[nlo + 2 * t + 1];
        xv.x *= di; xv.y *= di; xv.z *= di; xv.w = di;
        xf4[nlo + 2 * t + 1] = xv;
    }
    // cursors = absolute start offsets (reuse sdeg)
    sdeg[2 * t]     = e0 + excl;
    sdeg[2 * t + 1] = e0 + excl + a0;
    __syncthreads();
    for (int p = e0 + t; p < e1; p += 256) {
        int v = epack[p];
        int q = atomicAdd(&sdeg[v >> 17], 1);
        esrc[q] = v & 0x1FFFF;
    }
}

// Layer-1 aggregation -> u4 records. 16 lanes per node, 4 nodes per wave.
// xf4 pre-scaled by dinvs (dinvs in .w). Absolute CSR offsets.
static __global__ void gcn364_aggu(const int* __restrict__ esrc,
                                   const int* __restrict__ off,
                                   const float4* __restrict__ xf4,
                                   float4* __restrict__ u4, int N) {
    int lane = threadIdx.x & 63;
    int wv = threadIdx.x >> 6;
    int grp = lane >> 4;
    int sub = lane & 15;
    int i = (blockIdx.x * 4 + wv) * 4 + grp;

    float a0 = 0.f, a1 = 0.f, a2 = 0.f;
    if (i < N) {
        int p0 = (i == 0) ? 0 : off[i - 1];
        int p1 = off[i];
        for (int p = p0 + sub; p < p1; p += 16) {
            float4 sv = xf4[esrc[p]];
            a0 += sv.x; a1 += sv.y; a2 += sv.z;
        }
    }
    for (int d = 1; d < 16; d <<= 1) {
        a0 += __shfl_xor(a0, d);
        a1 += __shfl_xor(a1, d);
        a2 += __shfl_xor(a2, d);
    }
    if (i < N && sub == 0) {
        float4 xi = xf4[i];
        float di = xi.w;
        u4[i] = make_float4(di * (a0 + xi.x), di * (a1 + xi.y), di * (a2 + xi.z), di);
    }
}

// per-edge layer-1 row recompute + accumulate (packed dual-fp32)
__device__ __forceinline__ void gcn364_edge(const float4 u,
                                            const gcn364_f2* wa2, const gcn364_f2* wb2,
                                            const gcn364_f2* wc2, const gcn364_f2* bb2,
                                            gcn364_f2* acc) {
    gcn364_f2 ux = {u.x, u.x}, uy = {u.y, u.y}, uz = {u.z, u.z}, uw = {u.w, u.w};
    gcn364_f2 zero = {0.f, 0.f};
    #pragma unroll
    for (int q = 0; q < 4; q++) {
        gcn364_f2 t = ux * wa2[q] + uy * wb2[q] + uz * wc2[q] + bb2[q];
        t = __builtin_elementwise_max(t, zero);
        acc[q] += uw * t;
    }
}

// Fused layer-2 (R11-exact): per-edge on-the-fly layer-1 recompute +
// aggregation + GEMM + relu + mean-pool. MPB=16, group-per-node, 2-deep.
#define MPB 16
static __global__ __launch_bounds__(256, 8) void gcn364_agg2pool(
        const int* __restrict__ esrc, const int* __restrict__ off,
        const float4* __restrict__ u4,
        const float* __restrict__ w1f, const float* __restrict__ b1f,
        const float* __restrict__ w2f, const float* __restrict__ b2f,
        const int* __restrict__ batch, float* __restrict__ pooled, int N) {
    __shared__ float vsh[MPB][H];
    int i0 = blockIdx.x * MPB;
    int tid = threadIdx.x;
    int wave = tid >> 6;
    int lane = tid & 63;
    int grp = lane >> 4;
    int sub = lane & 15;
    int node = wave * 4 + grp;
    int i = i0 + node;

    gcn364_f2 wa2[4], wb2[4], wc2[4], bb2[4];
    #pragma unroll
    for (int q = 0; q < 4; q++) {
        int f = sub * 8 + q * 2;
        wa2[q] = (gcn364_f2){w1f[f], w1f[f + 1]};
        wb2[q] = (gcn364_f2){w1f[H + f], w1f[H + f + 1]};
        wc2[q] = (gcn364_f2){w1f[2 * H + f], w1f[2 * H + f + 1]};
        bb2[q] = (gcn364_f2){b1f[f], b1f[f + 1]};
    }

    gcn364_f2 acc[4];
    acc[0] = acc[1] = acc[2] = acc[3] = (gcn364_f2){0.f, 0.f};
    float di = 0.f;
    if (i < N) {
        int p0 = (i == 0) ? 0 : off[i - 1];
        int p1 = off[i];
        int p = p0;
        for (; p + 2 <= p1; p += 2) {
            float4 uA = u4[esrc[p]];
            float4 uB = u4[esrc[p + 1]];
            gcn364_edge(uA, wa2, wb2, wc2, bb2, acc);
            gcn364_edge(uB, wa2, wb2, wc2, bb2, acc);
        }
        if (p < p1) {
            float4 uA = u4[esrc[p]];
            gcn364_edge(uA, wa2, wb2, wc2, bb2, acc);
        }
        float4 uS = u4[i];   // self-loop
        gcn364_edge(uS, wa2, wb2, wc2, bb2, acc);
        di = uS.w;
    }
    *(float4*)&vsh[node][sub * 8 + 0] =
        make_float4(acc[0].x * di, acc[0].y * di, acc[1].x * di, acc[1].y * di);
    *(float4*)&vsh[node][sub * 8 + 4] =
        make_float4(acc[2].x * di, acc[2].y * di, acc[3].x * di, acc[3].y * di);
    __syncthreads();

    int f = tid & (H - 1);
    int half = tid >> 7;
    float bb = b2f[f];
    gcn364_f2 a2[8];
    #pragma unroll
    for (int n = 0; n < 8; n++) a2[n] = (gcn364_f2){0.f, 0.f};
    for (int k4 = 0; k4 < H / 4; k4++) {
        gcn364_f2 wlo = {w2f[(k4 * 4 + 0) * H + f], w2f[(k4 * 4 + 1) * H + f]};
        gcn364_f2 whi = {w2f[(k4 * 4 + 2) * H + f], w2f[(k4 * 4 + 3) * H + f]};
        #pragma unroll
        for (int n = 0; n < 8; n++) {
            float4 v = *(const float4*)&vsh[2 * n + half][k4 * 4];
            a2[n] += (gcn364_f2){v.x, v.y} * wlo + (gcn364_f2){v.z, v.w} * whi;
        }
    }

    float sum = 0.0f;
    int curg = -1;
    #pragma unroll
    for (int j = 0; j < 8; j++) {
        int ii = i0 + half + 2 * j;
        if (ii >= N) continue;
        float val = fmaxf(a2[j].x + a2[j].y + bb, 0.0f);
        int g = batch[ii];
        if (g != curg) {
            if (curg >= 0) atomicAdd(&pooled[curg * H + f], sum);
            curg = g;
            sum = 0.0f;
        }
        sum += val;
    }
    if (curg >= 0) atomicAdd(&pooled[curg * H + f], sum);
}

// out[g] = (pooled[g]/cnt_g) @ Wl + bl  -> detected dtype.
static __global__ void gcn364_final(const float* __restrict__ pooled,
                                    const int* __restrict__ batch,
                                    const float* __restrict__ wlf,
                                    const float* __restrict__ blf,
                                    const int* __restrict__ flag,
                                    void* __restrict__ out, int N, int G) {
    int g = blockIdx.x;
    int o = threadIdx.x;
    if (g >= G || o >= OUTF) return;
    int lo = 0, hi = N;
    while (lo < hi) { int m = (lo + hi) >> 1; if (batch[m] < g) lo = m + 1; else hi = m; }
    int a = lo;
    lo = 0; hi = N;
    while (lo < hi) { int m = (lo + hi) >> 1; if (batch[m] < g + 1) lo = m + 1; else hi = m; }
    float cn = (float)(lo - a);
    float inv = 1.0f / fmaxf(cn, 1.0f);
    float acc = 0.0f;
    for (int k = 0; k < H; k++)
        acc += pooled[g * H + k] * wlf[k * OUTF + o];
    float v = acc * inv + blf[o];
    if (*flag) ((float*)out)[g * OUTF + o] = v;
    else       ((unsigned short*)out)[g * OUTF + o] = gcn364_f2bf(v);
}

extern "C" void kernel_launch(void* const* d_in, const int* in_sizes, int n_in,
                              void* d_out, int out_size, void* d_ws, size_t ws_size,
                              hipStream_t stream) {
    const void* x  = d_in[0];
    const int* edge_index = (const int*)d_in[1];
    const int* batch      = (const int*)d_in[2];
    const void* W1 = d_in[3];
    const void* b1 = d_in[4];
    const void* W2 = d_in[5];
    const void* b2 = d_in[6];
    const void* Wl = d_in[7];
    const void* bl = d_in[8];

    const int N = in_sizes[0] / DIN;
    const int E = in_sizes[1] / 2;
    const int G = out_size / OUTF;
    const int* src = edge_index;
    const int* dst = edge_index + E;
    const int S  = (E + ECH - 1) / ECH;       // edge slices
    const int RG = (N + RGSIZE - 1) >> RGSH;  // node regions (must be <= 256)

    // ---- workspace layout; pooled zeroed (at ws start) ----
    char* wsb = (char*)d_ws;
    float* pooled     = (float*)wsb;                              // G*H (zeroed)
    int*   hist       = (int*)(pooled + (size_t)G * H);           // S*RG
    int*   regionBase = hist + (size_t)S * RG;                    // RG+1
    int*   off        = regionBase + RG + 1;                      // N
    int*   flag       = off + N;                                  // 1
    size_t ofs = (((size_t)((char*)(flag + 1) - wsb)) + 15) & ~(size_t)15;
    float4* xf4  = (float4*)(wsb + ofs);                          // N float4
    float4* u4   = xf4 + N;                                       // N float4
    float*  wf   = (float*)(u4 + N);                              // NWEIGHT
    int*    epack = (int*)(wf + NWEIGHT);                         // E
    int*    esrc  = epack + E;                                    // E

    float* w1f = wf;
    float* b1f = w1f + 384;
    float* w2f = b1f + 128;
    float* b2f = w2f + 16384;
    float* wlf = b2f + 128;
    float* blf = wlf + 1280;

    hipMemsetAsync(d_ws, 0, (size_t)G * H * 4, stream);

    {
        int convBlocks = (N + NWEIGHT + 255) / 256;
        int gmax = (S > convBlocks) ? S : convBlocks;
        gcn364_histconv<<<gmax, 256, 0, stream>>>(
            x, W1, b1, W2, b2, Wl, bl, flag, xf4, wf, dst, hist, N, E, S, RG);
    }
    gcn364_scanH<<<1, 256, 0, stream>>>(hist, regionBase, S, RG, E);
    gcn364_partition<<<S, 256, 0, stream>>>(src, dst, hist, regionBase, epack, E, RG);
    gcn364_build<<<RG, 256, 0, stream>>>(epack, regionBase, off, esrc, xf4, N);
    gcn364_aggu<<<(N + 15) / 16, 256, 0, stream>>>(esrc, off, xf4, u4, N);
    gcn364_agg2pool<<<(N + MPB - 1) / MPB, 256, 0, stream>>>(
        esrc, off, u4, w1f, b1f, w2f, b2f, batch, pooled, N);
    gcn364_final<<<G, 64, 0, stream>>>(pooled, batch, wlf, blf, flag, d_out, N, G);
}